// Round 1
// 393.732 us; speedup vs baseline: 1.0027x; 1.0027x over previous
//
#include <hip/hip_runtime.h>

// One workgroup (128 threads, 2 waves) per batch element b.
// Restructured: hidden dynamics are independent of output dynamics, so the
// 20-substep scan is factorized into
//   (1) barrier-free per-thread hidden trajectory -> hrate_all[s][h] in LDS
//   (2) one 80-thread LDS matmul for all I_out[s][g]
//   (3) a tiny 4-lane serial output chain (values[g] == raw I_out at s=19)
// This removes the 40 per-substep __syncthreads and the 5-deep dependent
// shuffle-reduce chains that made the previous version latency-bound
// (VALUBusy 20%, HBM 25% of peak).

namespace {

constexpr int F = 16;
constexpr int H = 128;
constexpr int G = 4;
constexpr int S = 20;
constexpr int HP = H + 1;   // padded trajectory stride (bank-conflict-free)

__device__ __forceinline__ float clip3(float x) {
    return fminf(fmaxf(x, -3.0f), 3.0f);
}

__global__ __launch_bounds__(128)
void spiking_critic_kernel(
    const float* __restrict__ energy,
    const float* __restrict__ threat,
    const float* __restrict__ food_visible,
    const int*   __restrict__ goal,
    const int*   __restrict__ prev_goal,
    const float* __restrict__ DA,
    const float* __restrict__ NA,
    const float* __restrict__ reward,
    const float* __restrict__ cls_probs,
    const float* __restrict__ W_in_w,
    const float* __restrict__ W_in_b,
    const float* __restrict__ W_out_w,
    const float* __restrict__ W_out_b,
    const float* __restrict__ hv_in,
    const float* __restrict__ hu_in,
    const float* __restrict__ hrate_in,
    const float* __restrict__ vv_in,
    const float* __restrict__ vu_in,
    const float* __restrict__ vrate_in,
    const float* __restrict__ elig_in,
    const float* __restrict__ elig_out,
    const float* __restrict__ prev_values,
    const float* __restrict__ prev_features,
    const float* __restrict__ noise,
    float* __restrict__ out_values,
    float* __restrict__ out_td,
    float* __restrict__ out_hidden,
    float* __restrict__ out_Win,
    float* __restrict__ out_Wout,
    float* __restrict__ out_ein,
    float* __restrict__ out_eout,
    int nB)
{
    const int b = blockIdx.x;
    const int t = threadIdx.x;          // 0..127

    __shared__ float w_out_lds[G * H];  // 2 KB (used in matmul + update)
    __shared__ float hrate_all[S * HP]; // 10.3 KB hidden-rate trajectory
    __shared__ float hrfin_lds[H];      // final hrate, aligned copy
    __shared__ float feat[F];
    __shared__ float pf_lds[F];
    __shared__ float iout_all[S * G];   // raw (biased, un-normalized) I_out
    __shared__ float wob[G];
    __shared__ float vrate_lds[G];
    __shared__ float red[2];
    __shared__ float tdsh;

    // ---- stage W_out into LDS (coalesced float4) + small vectors ----
    ((float4*)w_out_lds)[t] = ((const float4*)(W_out_w + (size_t)b * (G * H)))[t];
    if (t < F) pf_lds[t] = prev_features[(size_t)b * F + t];
    if (t < G) wob[t]    = W_out_b[(size_t)b * G + t];

    // ---- features (threads 0..15, one feature each) ----
    if (t < F) {
        float e = energy[b];
        float v;
        if      (t == 0)  v = e / 100.0f;
        else if (t == 1)  v = threat[b];
        else if (t == 2)  v = food_visible[b];
        else if (t == 3)  v = 1.0f - e / 100.0f;
        else if (t < 8)   v = (goal[b] == (t - 4)) ? 1.0f : 0.0f;
        else if (t < 13)  v = cls_probs[(size_t)b * 5 + (t - 8)];
        else if (t == 13) v = DA[b];
        else if (t == 14) v = NA[b];
        else              v = fmaxf(0.0f, 0.5f - e / 100.0f);
        feat[t] = v;
    }
    __syncthreads();

    // ---- I_in = W_in_w[b,t,:] . features + b  (row read straight from global;
    //      the 8 KB W_in block stays L1/L2-resident for the update phase) ----
    const float4* wrow = (const float4*)(W_in_w + ((size_t)b * H + t) * F);
    float dot = 0.0f;
    #pragma unroll
    for (int j = 0; j < 4; ++j) {
        float4 w = wrow[j];
        dot += w.x * feat[4 * j + 0] + w.y * feat[4 * j + 1]
             + w.z * feat[4 * j + 2] + w.w * feat[4 * j + 3];
    }
    float Iraw = dot + W_in_b[(size_t)b * H + t];
    float a = fabsf(Iraw);
    #pragma unroll
    for (int m = 32; m >= 1; m >>= 1) a += __shfl_xor(a, m, 64);
    if ((t & 63) == 0) red[t >> 6] = a;
    __syncthreads();
    const float meanI = (red[0] + red[1]) * (1.0f / 128.0f);
    const float Iin = Iraw * (5.0f / (meanI + 1e-8f));

    // ---- hidden state + noise prefetch ----
    float hv = hv_in[(size_t)b * H + t];
    float hu = hu_in[(size_t)b * H + t];
    float hr = hrate_in[(size_t)b * H + t];

    float nz[S];
    #pragma unroll
    for (int s = 0; s < S; ++s)
        nz[s] = noise[((size_t)s * nB + b) * H + t];

    // ---- 20 hidden substeps: pure per-thread VALU, ZERO barriers ----
    float hsp = 0.0f;
    #pragma unroll
    for (int s = 0; s < S; ++s) {
        float I  = Iin + 0.3f * nz[s];
        float vn = hv + (0.04f * hv * hv + 5.0f * hv + 140.0f - hu + I);
        float un = hu + 0.02f * (0.2f * hv - hu);
        float sp = (vn >= 30.0f) ? 1.0f : 0.0f;
        hv = (sp > 0.0f) ? -65.0f : vn;
        hu = un + sp * 8.0f;
        hr = 0.9f * hr + 0.1f * sp;
        hsp += sp;
        hrate_all[s * HP + t] = hr;   // stride 129: conflict-free write
    }
    hrfin_lds[t] = hr;
    __syncthreads();   // trajectory ready

    // ---- I_out[s][g] for ALL 20 steps at once: 80 independent dots ----
    if (t < S * G) {
        const int s = t >> 2;
        const int g = t & 3;
        const float* __restrict__ wr   = w_out_lds + g * H;
        const float* __restrict__ hrow = hrate_all + s * HP;
        float acc = 0.0f;
        #pragma unroll 8
        for (int i = 0; i < H; ++i) {
            int h = (i + t) & (H - 1);   // rotate start: spreads banks
            acc = fmaf(wr[h], hrow[h], acc);
        }
        iout_all[t] = acc + wob[g];      // raw, biased
    }
    __syncthreads();

    // ---- output-neuron chain: 4 lanes, trivially serial, no barriers ----
    if (t < G) {
        float vvv = vv_in[(size_t)b * G + t];
        float vuu = vu_in[(size_t)b * G + t];
        float vrr = vrate_in[(size_t)b * G + t];
        #pragma unroll
        for (int s = 0; s < S; ++s) {
            float i0 = iout_all[4 * s + 0];
            float i1 = iout_all[4 * s + 1];
            float i2 = iout_all[4 * s + 2];
            float i3 = iout_all[4 * s + 3];
            float m4 = 0.25f * (fabsf(i0) + fabsf(i1) + fabsf(i2) + fabsf(i3));
            float Io = iout_all[4 * s + t] * (4.0f / (m4 + 1e-8f));
            float vn = vvv + (0.04f * vvv * vvv + 5.0f * vvv + 140.0f - vuu + Io);
            float un = vuu + 0.02f * (0.2f * vvv - vuu);
            float sp = (vn >= 30.0f) ? 1.0f : 0.0f;
            vvv = (sp > 0.0f) ? -65.0f : vn;
            vuu = un + sp * 8.0f;
            vrr = 0.9f * vrr + 0.1f * sp;
        }
        vrate_lds[t] = vrr;
        // values = W_out @ hrate_final + b  ==  raw biased I_out at s = S-1
        out_values[(size_t)b * G + t] = iout_all[4 * (S - 1) + t];
    }

    // hidden_active: fraction of neurons that spiked at least once
    unsigned long long mb = __ballot(hsp > 0.0f);
    if ((t & 63) == 0) red[t >> 6] = (float)__popcll(mb);
    __syncthreads();

    if (t == 0) {
        float Vnow  = iout_all[4 * (S - 1) + goal[b]];
        float Vprev = prev_values[(size_t)b * G + prev_goal[b]];
        float td = reward[b] + 0.95f * Vnow - Vprev;
        out_td[b]     = td;
        out_hidden[b] = (red[0] + red[1]) * (1.0f / 128.0f);
        tdsh = td;
    }
    __syncthreads();

    const float td    = tdsh;
    const float scale = 1e-3f * td * DA[b];
    const bool  upd   = fabsf(td) > 1e-3f;

    // ---- elig_in / W_in update: 512 float4s, fully coalesced.
    //      W_in re-read from global (L1/L2-hot from the I_in phase). ----
    {
        const float4* ei4 = (const float4*)(elig_in + (size_t)b * (H * F));
        const float4* wi4 = (const float4*)(W_in_w  + (size_t)b * (H * F));
        float4* oW = (float4*)(out_Win + (size_t)b * (H * F));
        float4* oE = (float4*)(out_ein + (size_t)b * (H * F));
        const float4* pf4 = (const float4*)pf_lds;
        #pragma unroll
        for (int k = 0; k < 4; ++k) {
            int q = t + 128 * k;
            int h = q >> 2;
            int j = q & 3;
            float4 e  = ei4[q];
            float4 pf = pf4[j];
            float  hrv = hrfin_lds[h];
            float4 en;
            en.x = 0.9f * e.x + hrv * pf.x;
            en.y = 0.9f * e.y + hrv * pf.y;
            en.z = 0.9f * e.z + hrv * pf.z;
            en.w = 0.9f * e.w + hrv * pf.w;
            oE[q] = en;
            float4 w = wi4[q];
            float4 wn;
            if (upd) {
                wn.x = clip3(w.x + scale * en.x);
                wn.y = clip3(w.y + scale * en.y);
                wn.z = clip3(w.z + scale * en.z);
                wn.w = clip3(w.w + scale * en.w);
            } else {
                wn = w;
            }
            oW[q] = wn;
        }
    }

    // ---- elig_out / W_out update: 128 float4s ----
    {
        const float4* eo4 = (const float4*)(elig_out + (size_t)b * (G * H));
        float4* oW = (float4*)(out_Wout + (size_t)b * (G * H));
        float4* oE = (float4*)(out_eout + (size_t)b * (G * H));
        int q  = t;
        int gg = q >> 5;
        int h0 = (q & 31) * 4;
        float4 e  = eo4[q];
        float  vrv = vrate_lds[gg];
        float4 en;
        en.x = 0.9f * e.x + vrv * hrfin_lds[h0 + 0];
        en.y = 0.9f * e.y + vrv * hrfin_lds[h0 + 1];
        en.z = 0.9f * e.z + vrv * hrfin_lds[h0 + 2];
        en.w = 0.9f * e.w + vrv * hrfin_lds[h0 + 3];
        oE[q] = en;
        float4 w = ((const float4*)w_out_lds)[q];
        float4 wn;
        if (upd) {
            wn.x = clip3(w.x + scale * en.x);
            wn.y = clip3(w.y + scale * en.y);
            wn.z = clip3(w.z + scale * en.z);
            wn.w = clip3(w.w + scale * en.w);
        } else {
            wn = w;
        }
        oW[q] = wn;
    }
}

} // namespace

extern "C" void kernel_launch(void* const* d_in, const int* in_sizes, int n_in,
                              void* d_out, int out_size, void* d_ws, size_t ws_size,
                              hipStream_t stream) {
    const int nB = in_sizes[0];          // 8192

    float* out        = (float*)d_out;   // outputs concatenated flat
    float* out_values = out;
    float* out_td     = out_values + (size_t)nB * G;
    float* out_hidden = out_td + nB;
    float* out_Win    = out_hidden + nB;
    float* out_Wout   = out_Win + (size_t)nB * H * F;
    float* out_ein    = out_Wout + (size_t)nB * G * H;
    float* out_eout   = out_ein + (size_t)nB * H * F;

    spiking_critic_kernel<<<dim3(nB), dim3(128), 0, stream>>>(
        (const float*)d_in[0],  (const float*)d_in[1],  (const float*)d_in[2],
        (const int*)  d_in[3],  (const int*)  d_in[4],
        (const float*)d_in[5],  (const float*)d_in[6],  (const float*)d_in[7],
        (const float*)d_in[8],  (const float*)d_in[9],  (const float*)d_in[10],
        (const float*)d_in[11], (const float*)d_in[12], (const float*)d_in[13],
        (const float*)d_in[14], (const float*)d_in[15], (const float*)d_in[16],
        (const float*)d_in[17], (const float*)d_in[18], (const float*)d_in[19],
        (const float*)d_in[20], (const float*)d_in[21], (const float*)d_in[22],
        (const float*)d_in[23],
        out_values, out_td, out_hidden, out_Win, out_Wout, out_ein, out_eout,
        nB);
}